// Round 5
// baseline (328.274 us; speedup 1.0000x reference)
//
#include <hip/hip_runtime.h>

// Fused 2-layer LSTM (B=4096, T=512, I=H=32) + projection — bf16 split-precision MFMA.
// Round-5: 4 fat waves (256 thr). Each wave owns units 8wv..8wv+7 of BOTH layers
// (2 M-tiles L1 + 2 M-tiles L2). Per iteration i: L1 step i, L2 step i-1 (pipelined),
// all in one wave -> 4 independent cell chains interleaved by the compiler; 1 barrier/step.
//
// Chain-shortening: (a) L1's x-part (3 MFMAs, h-independent) precomputed one step ahead
// into pX -> only 3 dependent MFMAs after the h1 read; (b) L2 uses two parallel 3-chains
// (h1-input part e, h2-recurrent part f) merged with vector adds.
// Shared read: h1(i-1) fragment feeds BOTH L1 recurrence and L2 input (4 ds_reads, not 6).
//
// Weights persistent in registers, pre-scaled by -log2e (i,f,o) / -2log2e (g):
// sigmoid = rcp(1+exp2(acc)). D layout (row=(l>>4)*4+reg, col=l&15=batch): lane's acc
// regs = (i,f,g,o) of units u0=8wv+2g (tile m=0) / u0+1 (m=1) -> lane-local cell update.
// Split precision: W*d ~= Whi*(dhi+dlo) + Wlo*dhi (identical summand set to round 4).
//
// Buffers (parity par=i&1, parn=par^1): read H1[parn]=h1(i-1), H2[par]=h2(i-2);
// write H1[par]=h1(i), H2[parn]=h2(i-1). All cross-iter pairs barrier-separated.
// i=0: L2 compute runs on zeros but commit (c2, H2 write) is guarded -> h2(-1)=0 intact.
// Epilogue computes L2 step 511 from H1[1], H2[0].

typedef __attribute__((ext_vector_type(4))) float f32x4;
typedef __attribute__((ext_vector_type(8))) short s16x8;

#define MFMA_B16(a, b, c) __builtin_amdgcn_mfma_f32_16x16x32_bf16(a, b, c, 0, 0, 0)

namespace {
constexpr int TSTEPS = 512;
constexpr int CT     = 16;   // timesteps per x-staging chunk
constexpr int PITCH  = 40;   // shorts per (plane,batch) row: 80 B, 16B-aligned
constexpr float LOG2E = 1.4426950408889634f;

__device__ __forceinline__ ushort bf16rn(float x) {
    uint u = __float_as_uint(x);
    return (ushort)((u + 0x7FFFu + ((u >> 16) & 1u)) >> 16);
}
__device__ __forceinline__ float fromhi(ushort h) { return __uint_as_float(((uint)h) << 16); }

// acc = -log2e * z  ->  sigmoid(z) = rcp(1 + exp2(acc))
__device__ __forceinline__ float sigm2(float a) {
    return __builtin_amdgcn_rcpf(1.0f + __builtin_amdgcn_exp2f(a));
}

// Full gate set for one (unit,batch): acc = (i,f,g,o) pre-scaled preacts. Updates c.
__device__ __forceinline__ float act_gate(const f32x4 acc, float& c) {
    const float iv = sigm2(acc[0]);
    const float fv = sigm2(acc[1]);
    const float gv = fmaf(2.0f, sigm2(acc[2]), -1.0f);   // tanh(z) = 2*sigma(2z)-1
    const float ov = sigm2(acc[3]);
    const float cc = fmaf(fv, c, iv * gv);
    c = cc;
    return ov * fmaf(2.0f, sigm2(cc * (-2.0f * LOG2E)), -1.0f);
}

struct LayerW {
    s16x8 Whi[2][2];   // [m-tile][kt: 0=input-K, 1=recurrent-K]
    s16x8 Wlo[2][2];
    f32x4 bias[2];     // [m-tile]: (i,f,g,o) of unit u0+m, pre-scaled
};
}  // namespace

__global__ __launch_bounds__(256, 1)
void lstm2_v5(const float* __restrict__ x,
              const float* __restrict__ Wih1, const float* __restrict__ Whh1,
              const float* __restrict__ bih1, const float* __restrict__ bhh1,
              const float* __restrict__ Wih2, const float* __restrict__ Whh2,
              const float* __restrict__ bih2, const float* __restrict__ bhh2,
              const float* __restrict__ Wproj, const float* __restrict__ bproj,
              float* __restrict__ out)
{
    __shared__ __align__(16) ushort XA[CT * 2 * 16 * PITCH];  // 40 KB
    __shared__ __align__(16) ushort H1[2 * 2 * 16 * PITCH];   // 5 KB
    __shared__ __align__(16) ushort H2[2 * 2 * 16 * PITCH];   // 5 KB
    __shared__ float HF[16 * 33];
    __shared__ float WPs[16 * 33];
    __shared__ float BPs[16];

    const int tid  = threadIdx.x;
    const int wv   = tid >> 6;       // wave 0..3: owns units 8wv..8wv+7 of BOTH layers
    const int l    = tid & 63;
    const int colB = l & 15;         // batch (B col / A row / D col)
    const int g    = l >> 4;         // k-group; D row group
    const int u0   = wv * 8 + 2 * g; // lane's units (u0, u0+1) per layer

    // ---- persistent register weights, both layers, pre-scaled ----
    LayerW W[2];
    {
        const float* WIa[2] = {Wih1, Wih2};
        const float* WHa[2] = {Whh1, Whh2};
        const float* BIa[2] = {bih1, bih2};
        const float* BHa[2] = {bhh1, bhh2};
        const int q  = colB & 3;
        const int ut = (colB >> 2) * 2;
        const float sw = ((q == 2) ? -2.0f : -1.0f) * LOG2E;
#pragma unroll
        for (int L = 0; L < 2; ++L) {
#pragma unroll
            for (int m = 0; m < 2; ++m) {
                const int R = q * 32 + wv * 8 + ut + m;
#pragma unroll
                for (int kt = 0; kt < 2; ++kt) {
                    const float* src = (kt ? WHa[L] : WIa[L]) + R * 32 + g * 8;
#pragma unroll
                    for (int e = 0; e < 8; ++e) {
                        const float v = src[e] * sw;
                        const ushort hb = bf16rn(v);
                        W[L].Whi[m][kt][e] = (short)hb;
                        W[L].Wlo[m][kt][e] = (short)bf16rn(v - fromhi(hb));
                    }
                }
                f32x4 bb;
#pragma unroll
                for (int qq = 0; qq < 4; ++qq) {
                    const int Rb = qq * 32 + wv * 8 + 2 * g + m;
                    bb[qq] = (((qq == 2) ? -2.0f : -1.0f) * LOG2E) * (BIa[L][Rb] + BHa[L][Rb]);
                }
                W[L].bias[m] = bb;
            }
        }
    }

    for (int i = tid; i < 16 * 32; i += 256) WPs[(i >> 5) * 33 + (i & 31)] = Wproj[i];
    if (tid < 16) BPs[tid] = bproj[tid];
    for (int i = tid; i < 2 * 2 * 16 * PITCH; i += 256) { H1[i] = 0; H2[i] = 0; }

    const size_t bglob = (size_t)blockIdx.x * 16;

    // x staging: thread -> (batch sb, timestep st2); loads full 32-dim vector (8 float4)
    const int sb  = tid & 15;
    const int st2 = tid >> 4;        // 0..15
    const float* xsrc = x + ((bglob + sb) * TSTEPS + st2) * 32;

    float4 xv[8];
#pragma unroll
    for (int i = 0; i < 8; ++i) xv[i] = ((const float4*)xsrc)[i];

    float c1[2] = {0.f, 0.f}, c2[2] = {0.f, 0.f};
    f32x4 pX0, pX1;   // precomputed L1 x-part (bias + 3 x-MFMAs) for current step

    for (int t0 = 0; t0 < TSTEPS; t0 += CT) {
        // ---- write prefetched x chunk to XA (split bf16), prefetch next ----
#pragma unroll
        for (int qtr = 0; qtr < 4; ++qtr) {
            const float4 va = xv[qtr * 2], vb = xv[qtr * 2 + 1];
            const float v[8] = {va.x, va.y, va.z, va.w, vb.x, vb.y, vb.z, vb.w};
            s16x8 hi, lo;
#pragma unroll
            for (int e = 0; e < 8; ++e) {
                const ushort hb = bf16rn(v[e]);
                hi[e] = (short)hb;
                lo[e] = (short)bf16rn(v[e] - fromhi(hb));
            }
            *(s16x8*)&XA[((st2 * 2 + 0) * 16 + sb) * PITCH + qtr * 8] = hi;
            *(s16x8*)&XA[((st2 * 2 + 1) * 16 + sb) * PITCH + qtr * 8] = lo;
        }
        if (t0 + CT < TSTEPS) {
            const float4* p = (const float4*)(xsrc + (size_t)(t0 + CT) * 32);
#pragma unroll
            for (int i = 0; i < 8; ++i) xv[i] = p[i];
        }
        __syncthreads();   // XA ready

        // ---- precompute pX for tt=0 of this chunk ----
        {
            const s16x8 xh = *(const s16x8*)&XA[((0 * 2 + 0) * 16 + colB) * PITCH + g * 8];
            const s16x8 xl = *(const s16x8*)&XA[((0 * 2 + 1) * 16 + colB) * PITCH + g * 8];
            pX0 = W[0].bias[0];                  pX1 = W[0].bias[1];
            pX0 = MFMA_B16(W[0].Whi[0][0], xh, pX0); pX1 = MFMA_B16(W[0].Whi[1][0], xh, pX1);
            pX0 = MFMA_B16(W[0].Whi[0][0], xl, pX0); pX1 = MFMA_B16(W[0].Whi[1][0], xl, pX1);
            pX0 = MFMA_B16(W[0].Wlo[0][0], xh, pX0); pX1 = MFMA_B16(W[0].Wlo[1][0], xh, pX1);
        }

#pragma unroll 2
        for (int tt = 0; tt < CT; ++tt) {
            const int i = t0 + tt, par = i & 1, parn = par ^ 1;

            // ---- all LDS reads first (latency overlap) ----
            const s16x8 hh = *(const s16x8*)&H1[((parn * 2 + 0) * 16 + colB) * PITCH + g * 8];
            const s16x8 hl = *(const s16x8*)&H1[((parn * 2 + 1) * 16 + colB) * PITCH + g * 8];
            const s16x8 Hh = *(const s16x8*)&H2[((par * 2 + 0) * 16 + colB) * PITCH + g * 8];
            const s16x8 Hl = *(const s16x8*)&H2[((par * 2 + 1) * 16 + colB) * PITCH + g * 8];

            // ---- L1 step i: acc = pX + 3 h-MFMAs (the only dep chain after the read) ----
            f32x4 a0 = pX0, a1 = pX1;
            a0 = MFMA_B16(W[0].Whi[0][1], hh, a0); a1 = MFMA_B16(W[0].Whi[1][1], hh, a1);
            a0 = MFMA_B16(W[0].Whi[0][1], hl, a0); a1 = MFMA_B16(W[0].Whi[1][1], hl, a1);
            a0 = MFMA_B16(W[0].Wlo[0][1], hh, a0); a1 = MFMA_B16(W[0].Wlo[1][1], hh, a1);

            // ---- L2 step i-1: two parallel 3-chains, merged ----
            f32x4 e0 = W[1].bias[0], e1 = W[1].bias[1];
            f32x4 f0 = {0.f, 0.f, 0.f, 0.f}, f1 = {0.f, 0.f, 0.f, 0.f};
            e0 = MFMA_B16(W[1].Whi[0][0], hh, e0); e1 = MFMA_B16(W[1].Whi[1][0], hh, e1);
            e0 = MFMA_B16(W[1].Whi[0][0], hl, e0); e1 = MFMA_B16(W[1].Whi[1][0], hl, e1);
            e0 = MFMA_B16(W[1].Wlo[0][0], hh, e0); e1 = MFMA_B16(W[1].Wlo[1][0], hh, e1);
            f0 = MFMA_B16(W[1].Whi[0][1], Hh, f0); f1 = MFMA_B16(W[1].Whi[1][1], Hh, f1);
            f0 = MFMA_B16(W[1].Whi[0][1], Hl, f0); f1 = MFMA_B16(W[1].Whi[1][1], Hl, f1);
            f0 = MFMA_B16(W[1].Wlo[0][1], Hh, f0); f1 = MFMA_B16(W[1].Wlo[1][1], Hh, f1);

            // ---- precompute pX for step tt+1 (reads XA only; fills the pipe) ----
            if (tt < CT - 1) {
                const s16x8 xh = *(const s16x8*)&XA[(((tt + 1) * 2 + 0) * 16 + colB) * PITCH + g * 8];
                const s16x8 xl = *(const s16x8*)&XA[(((tt + 1) * 2 + 1) * 16 + colB) * PITCH + g * 8];
                pX0 = W[0].bias[0];                  pX1 = W[0].bias[1];
                pX0 = MFMA_B16(W[0].Whi[0][0], xh, pX0); pX1 = MFMA_B16(W[0].Whi[1][0], xh, pX1);
                pX0 = MFMA_B16(W[0].Whi[0][0], xl, pX0); pX1 = MFMA_B16(W[0].Whi[1][0], xl, pX1);
                pX0 = MFMA_B16(W[0].Wlo[0][0], xh, pX0); pX1 = MFMA_B16(W[0].Wlo[1][0], xh, pX1);
            }

            // ---- L1 activations + h1 write -> H1[par] ----
            {
                float h0 = act_gate(a0, c1[0]);
                float h1v = act_gate(a1, c1[1]);
                const ushort p0 = bf16rn(h0), p1 = bf16rn(h1v);
                const ushort q0 = bf16rn(h0 - fromhi(p0)), q1 = bf16rn(h1v - fromhi(p1));
                *(uint*)&H1[((par * 2 + 0) * 16 + colB) * PITCH + u0] = (uint)p0 | ((uint)p1 << 16);
                *(uint*)&H1[((par * 2 + 1) * 16 + colB) * PITCH + u0] = (uint)q0 | ((uint)q1 << 16);
            }

            // ---- L2 activations + h2 write -> H2[parn] (guarded at i=0) ----
            if (i > 0) {
                const f32x4 b0 = e0 + f0, b1 = e1 + f1;
                float h0 = act_gate(b0, c2[0]);
                float h1v = act_gate(b1, c2[1]);
                const ushort p0 = bf16rn(h0), p1 = bf16rn(h1v);
                const ushort q0 = bf16rn(h0 - fromhi(p0)), q1 = bf16rn(h1v - fromhi(p1));
                *(uint*)&H2[((parn * 2 + 0) * 16 + colB) * PITCH + u0] = (uint)p0 | ((uint)p1 << 16);
                *(uint*)&H2[((parn * 2 + 1) * 16 + colB) * PITCH + u0] = (uint)q0 | ((uint)q1 << 16);
            }

            __syncthreads();   // the ONE barrier per step
        }
    }

    // ---- epilogue: L2 step 511 from H1[1] (h1(511)) and H2[0] (h2(510)) ----
    {
        const s16x8 hh = *(const s16x8*)&H1[((1 * 2 + 0) * 16 + colB) * PITCH + g * 8];
        const s16x8 hl = *(const s16x8*)&H1[((1 * 2 + 1) * 16 + colB) * PITCH + g * 8];
        const s16x8 Hh = *(const s16x8*)&H2[((0 * 2 + 0) * 16 + colB) * PITCH + g * 8];
        const s16x8 Hl = *(const s16x8*)&H2[((0 * 2 + 1) * 16 + colB) * PITCH + g * 8];
        f32x4 e0 = W[1].bias[0], e1 = W[1].bias[1];
        f32x4 f0 = {0.f, 0.f, 0.f, 0.f}, f1 = {0.f, 0.f, 0.f, 0.f};
        e0 = MFMA_B16(W[1].Whi[0][0], hh, e0); e1 = MFMA_B16(W[1].Whi[1][0], hh, e1);
        e0 = MFMA_B16(W[1].Whi[0][0], hl, e0); e1 = MFMA_B16(W[1].Whi[1][0], hl, e1);
        e0 = MFMA_B16(W[1].Wlo[0][0], hh, e0); e1 = MFMA_B16(W[1].Wlo[1][0], hh, e1);
        f0 = MFMA_B16(W[1].Whi[0][1], Hh, f0); f1 = MFMA_B16(W[1].Whi[1][1], Hh, f1);
        f0 = MFMA_B16(W[1].Whi[0][1], Hl, f0); f1 = MFMA_B16(W[1].Whi[1][1], Hl, f1);
        f0 = MFMA_B16(W[1].Wlo[0][1], Hh, f0); f1 = MFMA_B16(W[1].Wlo[1][1], Hh, f1);
        const f32x4 b0 = e0 + f0, b1 = e1 + f1;
        HF[colB * 33 + u0]     = act_gate(b0, c2[0]);
        HF[colB * 33 + u0 + 1] = act_gate(b1, c2[1]);
    }
    __syncthreads();

    // ---- projection: out[b][m], 256 threads ----
    {
        const int b = tid >> 4, m = tid & 15;
        float a = BPs[m];
        const float* hp = &HF[b * 33];
        const float* wp = &WPs[m * 33];
#pragma unroll
        for (int k = 0; k < 32; ++k) a = fmaf(hp[k], wp[k], a);
        out[(bglob + b) * 16 + m] = a;
    }
}

extern "C" void kernel_launch(void* const* d_in, const int* in_sizes, int n_in,
                              void* d_out, int out_size, void* d_ws, size_t ws_size,
                              hipStream_t stream) {
    const float* x     = (const float*)d_in[0];
    const float* Wih1  = (const float*)d_in[1];
    const float* Whh1  = (const float*)d_in[2];
    const float* bih1  = (const float*)d_in[3];
    const float* bhh1  = (const float*)d_in[4];
    const float* Wih2  = (const float*)d_in[5];
    const float* Whh2  = (const float*)d_in[6];
    const float* bih2  = (const float*)d_in[7];
    const float* bhh2  = (const float*)d_in[8];
    const float* Wproj = (const float*)d_in[9];
    const float* bproj = (const float*)d_in[10];
    float* out = (float*)d_out;

    dim3 grid(256), block(256);
    lstm2_v5<<<grid, block, 0, stream>>>(x, Wih1, Whh1, bih1, bhh1,
                                         Wih2, Whh2, bih2, bhh2,
                                         Wproj, bproj, out);
}

// Round 6
// 205.564 us; speedup vs baseline: 1.5969x; 1.5969x over previous
//
#include <hip/hip_runtime.h>

// Fused 2-layer LSTM (B=4096, T=512, I=H=32) + projection — PLAIN FP16 MFMA, 16 waves.
//
// Precision: all matmul operands fp16 (rn), fp32 accumulate. Est. final err ~2e-3 vs
// 5.117e-3 threshold (fp16 2^-12 rel; bf16 would be ~8x worse -> rejected).
// Fallback if absmax fails: split-bf16 in this same structure.
//
// Structure: grid 256 x 1024 thr = 16 waves (4/SIMD — the round-5 lesson: waves/SIMD
// dominates). Waves 0-7: L1 tile t=wv (16 gate rows, units t*4..t*4+3); waves 8-15: L2
// tile t=wv-8. Layer-pipelined: iter i computes L1 step i and L2 step i-1; 1 barrier/iter.
// Lane owns ONE cell (unit u=t*4+g, batch colB): D regs = (i,f,g,o) -> lane-local update,
// 10 trans/lane/step. L1: pX = bias + MFMA(Wi, x(t+1)) precomputed a step ahead -> in-step
// chain = 1 MFMA. L2: e = bias+MFMA(Wi,h1), f = MFMA(Wr,h2) parallel, merged by v_add.
//
// LDS frag-unit layout (16B half8 units), kg-XOR swizzle col^(kg<<1) -> balanced banks.
// Buffers: iter i: L1 reads H1[parn]=h1(i-1), writes H1[par]; L2 reads H1[parn], H2[par]
// =h2(i-2), writes H2[parn]=h2(i-1). All cross-iter pairs barrier-separated (round-4 proof).
// i=0: L2 commit guarded. Epilogue: L2 computes step 511 from H1[1], H2[0].

typedef __attribute__((ext_vector_type(4))) float f32x4;
typedef _Float16 half8 __attribute__((ext_vector_type(8)));

#define MFMA_F16(a, b, c) __builtin_amdgcn_mfma_f32_16x16x32_f16(a, b, c, 0, 0, 0)

namespace {
constexpr int TSTEPS = 512;
constexpr int CT     = 16;
constexpr float LOG2E = 1.4426950408889634f;

// acc = -log2e * z  ->  sigmoid(z) = rcp(1 + exp2(acc))
__device__ __forceinline__ float sigm2(float a) {
    return __builtin_amdgcn_rcpf(1.0f + __builtin_amdgcn_exp2f(a));
}

// acc = (i,f,g,o) pre-scaled preacts of one cell; updates c, returns h.
__device__ __forceinline__ float act_gate(const f32x4 acc, float& c) {
    const float iv = sigm2(acc[0]);
    const float fv = sigm2(acc[1]);
    const float gv = fmaf(2.0f, sigm2(acc[2]), -1.0f);   // tanh(z) = 2*sigma(2z)-1
    const float ov = sigm2(acc[3]);
    const float cc = fmaf(fv, c, iv * gv);
    c = cc;
    return ov * fmaf(2.0f, sigm2(cc * (-2.0f * LOG2E)), -1.0f);
}
}  // namespace

__global__ __launch_bounds__(1024, 1)
void lstm2_v6(const float* __restrict__ x,
              const float* __restrict__ Wih1, const float* __restrict__ Whh1,
              const float* __restrict__ bih1, const float* __restrict__ bhh1,
              const float* __restrict__ Wih2, const float* __restrict__ Whh2,
              const float* __restrict__ bih2, const float* __restrict__ bhh2,
              const float* __restrict__ Wproj, const float* __restrict__ bproj,
              float* __restrict__ out)
{
    // frag-unit layout: frag index = slab*64 + kg*16 + (col ^ (kg<<1)); 16B per frag
    __shared__ half8 XA[CT * 4 * 16];   // 16 KB: x chunk   (slab = tt)
    __shared__ half8 H1[2 * 4 * 16];    // 2 KB             (slab = parity)
    __shared__ half8 H2[2 * 4 * 16];    // 2 KB
    __shared__ float HF[16 * 33];
    __shared__ float WPs[16 * 33];
    __shared__ float BPs[16];

    const int tid  = threadIdx.x;
    const int wv   = tid >> 6;        // 0..15
    const int Lly  = wv >> 3;         // 0: L1 waves, 1: L2 waves
    const int t    = wv & 7;          // M-tile (units t*4..t*4+3)
    const int l    = tid & 63;
    const int colB = l & 15;          // batch (B col / A row / D col)
    const int g    = l >> 4;          // k-group; D row group -> lane's unit = t*4+g

    // ---- persistent fp16 register weights (A-frags), unit-major reorder, pre-scaled ----
    // A row rA -> gate q=rA&3, unit t*4+(rA>>2); original row R = q*32 + t*4 + (rA>>2)
    half8 Wi, Wr;
    f32x4 bias;
    {
        const float* WI = Lly ? Wih2 : Wih1;
        const float* WH = Lly ? Whh2 : Whh1;
        const float* BI = Lly ? bih2 : bih1;
        const float* BH = Lly ? bhh2 : bhh1;
        const int q = colB & 3;
        const int R = q * 32 + t * 4 + (colB >> 2);
        const float sw = ((q == 2) ? -2.0f : -1.0f) * LOG2E;
#pragma unroll
        for (int e = 0; e < 8; ++e) {
            Wi[e] = (_Float16)(WI[R * 32 + g * 8 + e] * sw);
            Wr[e] = (_Float16)(WH[R * 32 + g * 8 + e] * sw);
        }
#pragma unroll
        for (int qq = 0; qq < 4; ++qq) {
            const int Rb = qq * 32 + t * 4 + g;
            bias[qq] = (((qq == 2) ? -2.0f : -1.0f) * LOG2E) * (BI[Rb] + BH[Rb]);
        }
    }

    for (int i = tid; i < 16 * 32; i += 1024) WPs[(i >> 5) * 33 + (i & 31)] = Wproj[i];
    if (tid < 16) BPs[tid] = bproj[tid];
    {   // zero h state
        ushort* z1 = (ushort*)H1;
        ushort* z2 = (ushort*)H2;
        for (int i = tid; i < 2 * 4 * 16 * 8; i += 1024) { z1[i] = 0; z2[i] = 0; }
    }

    const size_t bglob = (size_t)blockIdx.x * 16;

    // lane's read-frag base (kg = g) and h-write scalar index components
    const int fbase = g * 16 + (colB ^ (g << 1));          // + slab*64
    const int kgw   = t >> 1;                              // frag kg holding unit t*4+g
    const int hbw   = (kgw * 16 + (colB ^ (kgw << 1))) * 8 + (t & 1) * 4 + g;  // + par*512
    const int unit  = t * 4 + g;

    // x staging: thread -> (step st, batch sb, k-group kg); 32B global load, 16B LDS write
    const int kg = tid & 3;
    const int sb = (tid >> 2) & 15;
    const int st = tid >> 6;   // 0..15
    const float* xsrc = x + ((bglob + sb) * TSTEPS + st) * 32 + kg * 8;
    const int xslot = st * 64 + kg * 16 + (sb ^ (kg << 1));

    float4 xv0 = ((const float4*)xsrc)[0], xv1 = ((const float4*)xsrc)[1];

    float c = 0.f;     // lane's cell state (L1 or L2 per wave role)
    f32x4 pX;          // L1: precomputed bias + x-part for current step

    for (int t0 = 0; t0 < TSTEPS; t0 += CT) {
        // ---- write prefetched x chunk (fp16), prefetch next ----
        {
            half8 hv;
#pragma unroll
            for (int e = 0; e < 4; ++e) { hv[e] = (_Float16)xv0[e]; hv[4 + e] = (_Float16)xv1[e]; }
            XA[xslot] = hv;
        }
        if (t0 + CT < TSTEPS) {
            const float4* p = (const float4*)(xsrc + (size_t)(t0 + CT) * 32);
            xv0 = p[0]; xv1 = p[1];
        }
        __syncthreads();   // XA ready (also orders vs. prior chunk's reads)

        if (Lly == 0) {    // pX for tt=0 of this chunk
            pX = bias;
            pX = MFMA_F16(Wi, XA[0 * 64 + fbase], pX);
        }

#pragma unroll 2
        for (int tt = 0; tt < CT; ++tt) {
            const int i = t0 + tt, par = i & 1, parn = par ^ 1;

            if (Lly == 0) {
                // ---- L1 step i: chain = 1 MFMA after the h1 read ----
                const half8 hf = H1[parn * 64 + fbase];
                f32x4 a = pX;
                a = MFMA_F16(Wr, hf, a);
                if (tt < CT - 1) {            // precompute pX for step tt+1 (XA only)
                    pX = bias;
                    pX = MFMA_F16(Wi, XA[(tt + 1) * 64 + fbase], pX);
                }
                const float h = act_gate(a, c);
                ((_Float16*)H1)[par * 512 + hbw] = (_Float16)h;
            } else {
                // ---- L2 step i-1: two parallel 1-chains, merged ----
                const half8 hf = H1[parn * 64 + fbase];
                const half8 Hf = H2[par * 64 + fbase];
                f32x4 e_ = bias;
                f32x4 f_ = {0.f, 0.f, 0.f, 0.f};
                e_ = MFMA_F16(Wi, hf, e_);
                f_ = MFMA_F16(Wr, Hf, f_);
                if (i > 0) {
                    const float h = act_gate(e_ + f_, c);
                    ((_Float16*)H2)[parn * 512 + hbw] = (_Float16)h;
                }
            }
            __syncthreads();   // the ONE barrier per step
        }
    }

    // ---- epilogue: L2 step 511 from H1[1] (h1(511)) and H2[0] (h2(510)) ----
    if (Lly == 1) {
        const half8 hf = H1[1 * 64 + fbase];
        const half8 Hf = H2[0 * 64 + fbase];
        f32x4 e_ = bias;
        f32x4 f_ = {0.f, 0.f, 0.f, 0.f};
        e_ = MFMA_F16(Wi, hf, e_);
        f_ = MFMA_F16(Wr, Hf, f_);
        HF[colB * 33 + unit] = act_gate(e_ + f_, c);
    }
    __syncthreads();

    // ---- projection: out[b][m] ----
    if (tid < 256) {
        const int b = tid >> 4, m = tid & 15;
        float a = BPs[m];
        const float* hp = &HF[b * 33];
        const float* wp = &WPs[m * 33];
#pragma unroll
        for (int k = 0; k < 32; ++k) a = fmaf(hp[k], wp[k], a);
        out[(bglob + b) * 16 + m] = a;
    }
}

extern "C" void kernel_launch(void* const* d_in, const int* in_sizes, int n_in,
                              void* d_out, int out_size, void* d_ws, size_t ws_size,
                              hipStream_t stream) {
    const float* x     = (const float*)d_in[0];
    const float* Wih1  = (const float*)d_in[1];
    const float* Whh1  = (const float*)d_in[2];
    const float* bih1  = (const float*)d_in[3];
    const float* bhh1  = (const float*)d_in[4];
    const float* Wih2  = (const float*)d_in[5];
    const float* Whh2  = (const float*)d_in[6];
    const float* bih2  = (const float*)d_in[7];
    const float* bhh2  = (const float*)d_in[8];
    const float* Wproj = (const float*)d_in[9];
    const float* bproj = (const float*)d_in[10];
    float* out = (float*)d_out;

    dim3 grid(256), block(1024);
    lstm2_v6<<<grid, block, 0, stream>>>(x, Wih1, Whh1, bih1, bhh1,
                                         Wih2, Whh2, bih2, bhh2,
                                         Wproj, bproj, out);
}